// Round 9
// baseline (139.059 us; speedup 1.0000x reference)
//
#include <hip/hip_runtime.h>
#include <hip/hip_bf16.h>

#define NNODE 512
#define CCH   16
#define TT    15
#define TP    16
#define HH    32
#define DD    32

typedef unsigned short u16;
typedef unsigned int   u32;
typedef short bf8 __attribute__((ext_vector_type(8)));   // 8 bf16 = 4 VGPR (MFMA A/B frag)
typedef float f4  __attribute__((ext_vector_type(4)));   // MFMA C/D frag

__device__ __forceinline__ float bf2f(u16 v) {
    union { u32 u; float f; } x; x.u = ((u32)v) << 16; return x.f;
}
__device__ __forceinline__ u16 f2bf(float f) {
    union { float f; u32 u; } x; x.f = f;
    u32 u = x.u;
    return (u16)((u + 0x7FFFu + ((u >> 16) & 1u)) >> 16);
}
__device__ __forceinline__ void unpack8(uint4 p, float* o) {
    o[0]=bf2f((u16)(p.x & 0xffffu)); o[1]=bf2f((u16)(p.x >> 16));
    o[2]=bf2f((u16)(p.y & 0xffffu)); o[3]=bf2f((u16)(p.y >> 16));
    o[4]=bf2f((u16)(p.z & 0xffffu)); o[5]=bf2f((u16)(p.z >> 16));
    o[6]=bf2f((u16)(p.w & 0xffffu)); o[7]=bf2f((u16)(p.w >> 16));
}
__device__ __forceinline__ uint4 pack8(const u16* v) {
    return make_uint4((u32)v[0]|((u32)v[1]<<16), (u32)v[2]|((u32)v[3]<<16),
                      (u32)v[4]|((u32)v[5]<<16), (u32)v[6]|((u32)v[7]<<16));
}

// ---------------------------------------------------------------------------
// K1: blocks 0..511: per-node prep (A1/B1/Qb/QAd/QB/A2T/B2T).
//     blocks 512..767: 32x32 adjacency tiles -> adjP + adjPT (diag folded).
//     block 512 additionally zeroes the 64 gemm2 tile-counters.
// ---------------------------------------------------------------------------
__global__ __launch_bounds__(256) void k_prep_adjp(
    const float* __restrict__ x, const float* __restrict__ W1,
    const float* __restrict__ W2, const float* __restrict__ W3,
    const float* __restrict__ adj,
    u16* __restrict__ A1, u16* __restrict__ B1,
    u16* __restrict__ A2T, u16* __restrict__ B2T,
    u16* __restrict__ Qb, float* __restrict__ QAd, float* __restrict__ QB,
    u16* __restrict__ adjP, u16* __restrict__ adjPT, int* __restrict__ cnt)
{
    int tid = threadIdx.x;
    if (blockIdx.x < 512) {
        int n = blockIdx.x;
        __shared__ alignas(16) float xs[CCH];
        __shared__ alignas(16) float A1row[512], B1row[512];
        __shared__ alignas(16) float A2row[512], B2row[512];
        __shared__ alignas(16) float Qs[HH];
        if (tid < CCH) xs[tid] = x[n*CCH + tid];
        __syncthreads();
        float xr[CCH];
        #pragma unroll
        for (int i=0;i<CCH;i++) xr[i]=xs[i];
        #pragma unroll
        for (int rep=0; rep<2; rep++) {
            int c = tid + rep*256;
            float a1=0.f,b1=0.f,a2=0.f,b2=0.f;
            #pragma unroll
            for (int i=0;i<CCH;i++) {
                a1 += xr[i]*W1[i*512 + c];
                b1 += xr[i]*W1[(CCH+i)*512 + c];
                a2 += xr[i]*W2[i*512 + c];
                b2 += xr[i]*W2[(CCH+i)*512 + c];
            }
            A1[(size_t)n*512 + c]=f2bf(a1); B1[(size_t)n*512 + c]=f2bf(b1);
            A1row[c]=a1; B1row[c]=b1; A2row[c]=a2; B2row[c]=b2;
        }
        if (tid < HH) {
            float q=0.f;
            #pragma unroll
            for (int i=0;i<CCH;i++) q += xr[i]*W3[i*HH + tid];
            Qs[tid]=q; Qb[(size_t)n*HH + tid]=f2bf(q);
        }
        __syncthreads();
        if (tid < TP) {
            float qa=0.f, qb=0.f;
            #pragma unroll
            for (int h=0;h<HH;h++) { qa += Qs[h]*A1row[tid*HH+h]; qb += Qs[h]*B1row[tid*HH+h]; }
            QAd[(size_t)n*TP + tid]=qa; QB[(size_t)n*TP + tid]=qb;
        }
        {   // A2T/B2T: [d][n*16+t]; coalesced u32 stores
            int d = tid >> 3, t0 = (tid & 7) * 2;
            u32 pa = (u32)f2bf(A2row[t0*32 + d]) | ((u32)f2bf(A2row[(t0+1)*32 + d]) << 16);
            u32 pb = (u32)f2bf(B2row[t0*32 + d]) | ((u32)f2bf(B2row[(t0+1)*32 + d]) << 16);
            *(u32*)(A2T + (size_t)d*8192 + n*16 + t0) = pa;
            *(u32*)(B2T + (size_t)d*8192 + n*16 + t0) = pb;
        }
    } else {
        int b = blockIdx.x - 512;            // 0..255
        if (b == 0 && tid < 64) cnt[tid] = 0;    // zero gemm2 tile tickets
        int n0 = (b >> 4) * 32, m0 = (b & 15) * 32;
        __shared__ alignas(16) u16 s[32*520];  // stride 520 (1040B=65*16)
        #pragma unroll
        for (int i = 0; i < 60; i++) {
            int e = tid + i*256;
            int nl = e / 480; int rem = e - nl*480;
            int ml = rem / 15; int t = rem - ml*15;
            float v = adj[((size_t)(n0+nl)*512 + (m0+ml))*TT + t];
            s[nl*520 + ml*16 + t] = f2bf(v);
        }
        #pragma unroll
        for (int i = 0; i < 4; i++) {
            int e = tid + i*256; int nl = e >> 5, ml = e & 31;
            s[nl*520 + ml*16 + 15] = ((n0+nl) == (m0+ml)) ? (u16)0x3F80 : (u16)0;
        }
        __syncthreads();
        #pragma unroll
        for (int i = 0; i < 8; i++) {        // adjP: 32 rows x 1KB
            int c = tid + i*256;
            int nl = c >> 6, off = (c & 63) * 8;
            uint4 vv = *(const uint4*)(s + nl*520 + off);
            *(uint4*)(adjP + (size_t)(n0+nl)*8192 + m0*16 + off) = vv;
        }
        #pragma unroll
        for (int i = 0; i < 8; i++) {        // adjPT: 32 rows x 1KB (transposed)
            int c = tid + i*256;
            int ml = c >> 6, nlh = c & 63, nl = nlh >> 1, half = nlh & 1;
            uint4 vv = *(const uint4*)(s + nl*520 + ml*16 + half*8);
            *(uint4*)(adjPT + (size_t)(m0+ml)*8192 + (n0+nl)*16 + half*8) = vv;
        }
    }
}

// ---------------------------------------------------------------------------
// K2: fused logits: MFMA the directed dot-tensors, combine in-register,
// t-sum via 16-lane xor shuffles. L2 written transposed.
// ---------------------------------------------------------------------------
__global__ __launch_bounds__(256) void k_logits(
    const u16* __restrict__ Qb, const u16* __restrict__ A1, const u16* __restrict__ B1,
    const u16* __restrict__ adjP, const u16* __restrict__ adjPT,
    const float* __restrict__ QAd, const float* __restrict__ QB,
    float* __restrict__ L1, float* __restrict__ L2T)
{
    const int m0 = blockIdx.x * 16, n0 = blockIdx.y * 16;
    const int tid = threadIdx.x;
    const int wv = tid >> 6, lane = tid & 63, l15 = lane & 15, quad = lane >> 4;
    __shared__ alignas(16) float sL1[16*17];
    __shared__ alignas(16) float sL2[16*17];

    bf8 afragN = *(const bf8*)(Qb + (size_t)(n0 + l15)*32 + quad*8);
    bf8 afragM = *(const bf8*)(Qb + (size_t)(m0 + l15)*32 + quad*8);

    f4 accG[4], accH[4];
    #pragma unroll
    for (int j = 0; j < 4; j++) {
        int m = m0 + wv*4 + j;
        int n = n0 + wv*4 + j;
        bf8 bG = *(const bf8*)(A1 + (size_t)m*512 + l15*32 + quad*8);
        bf8 bH = *(const bf8*)(B1 + (size_t)n*512 + l15*32 + quad*8);
        f4 z = {0.f,0.f,0.f,0.f};
        accG[j] = __builtin_amdgcn_mfma_f32_16x16x32_bf16(afragN, bG, z, 0, 0, 0);
        accH[j] = __builtin_amdgcn_mfma_f32_16x16x32_bf16(afragM, bH, z, 0, 0, 0);
    }

    #pragma unroll
    for (int j = 0; j < 4; j++) {
        int m = m0 + wv*4 + j;
        #pragma unroll
        for (int r = 0; r < 4; r++) {
            int n = n0 + quad*4 + r;
            float a  = bf2f(adjP [(size_t)n*8192 + m*16 + l15]);
            float at = bf2f(adjPT[(size_t)n*8192 + m*16 + l15]);
            float v = a*accG[j][r] + at*QB[n*16 + l15];
            #pragma unroll
            for (int o = 1; o < 16; o <<= 1) v += __shfl_xor(v, o, 64);
            if (l15 == 0) sL1[(quad*4+r)*17 + wv*4 + j] = v;
        }
    }
    #pragma unroll
    for (int j = 0; j < 4; j++) {
        int n = n0 + wv*4 + j;
        #pragma unroll
        for (int r = 0; r < 4; r++) {
            int m = m0 + quad*4 + r;
            float a  = bf2f(adjP [(size_t)n*8192 + m*16 + l15]);
            float at = bf2f(adjPT[(size_t)n*8192 + m*16 + l15]);
            float v = a*QAd[m*16 + l15] + at*accH[j][r];
            #pragma unroll
            for (int o = 1; o < 16; o <<= 1) v += __shfl_xor(v, o, 64);
            if (l15 == 0) sL2[(quad*4+r)*17 + wv*4 + j] = v;
        }
    }
    __syncthreads();
    int row = tid >> 4, col = tid & 15;
    L1 [(size_t)(n0+row)*NNODE + m0 + col] = sL1[row*17+col];
    L2T[(size_t)(m0+row)*NNODE + n0 + col] = sL2[row*17+col];
}

// ---------------------------------------------------------------------------
// K3: softmax over a 512-row + FUSED W-build and u/v reduction.
// ---------------------------------------------------------------------------
__global__ __launch_bounds__(256) void k_softmax_w(
    const float* __restrict__ L1, const float* __restrict__ L2T,
    const u16* __restrict__ adjP, const u16* __restrict__ adjPT,
    u16* __restrict__ W1c, u16* __restrict__ W2c,
    float* __restrict__ u1, float* __restrict__ v2)
{
    int b = blockIdx.x, tid = threadIdx.x;
    bool first = b < NNODE;
    int j = first ? b : b - NNODE;
    const float* row = first ? (L1 + (size_t)j*NNODE) : (L2T + (size_t)j*NNODE);
    u16* W  = (first ? W1c : W2c) + (size_t)j*8192;
    float* uv = (first ? u1 : v2) + (size_t)j*TP;

    float v0 = row[tid], v1 = row[tid+256];
    float mx = fmaxf(v0, v1);
    #pragma unroll
    for (int o=32; o; o>>=1) mx = fmaxf(mx, __shfl_xor(mx, o, 64));
    __shared__ alignas(16) float red[4], red2[4], ur[4][16];
    int lane = tid & 63, wv = tid >> 6;
    if (!lane) red[wv] = mx;
    __syncthreads();
    mx = fmaxf(fmaxf(red[0],red[1]), fmaxf(red[2],red[3]));
    float e0 = __expf(v0 - mx), e1 = __expf(v1 - mx);
    float sm = e0 + e1;
    #pragma unroll
    for (int o=32; o; o>>=1) sm += __shfl_xor(sm, o, 64);
    if (!lane) red2[wv] = sm;
    __syncthreads();
    float inv = 1.0f / (red2[0]+red2[1]+red2[2]+red2[3]);
    float sa = e0*inv, sb = e1*inv;

    const u16* ap = adjP  + (size_t)j*8192;
    const u16* tp = adjPT + (size_t)j*8192;
    float u[16];
    #pragma unroll
    for (int t=0;t<16;t++) u[t]=0.f;
    #pragma unroll
    for (int half = 0; half < 2; half++) {
        int k = tid + half*256;
        float sv = half ? sb : sa;
        const uint4* p = (const uint4*)(ap + k*16);
        float av[16]; unpack8(p[0], av); unpack8(p[1], av+8);
        u16 o16[16];
        #pragma unroll
        for (int t=0;t<16;t++) o16[t] = f2bf(sv*av[t]);
        uint4* wp = (uint4*)(W + k*16);
        wp[0] = pack8(o16); wp[1] = pack8(o16+8);
        const uint4* q = (const uint4*)(tp + k*16);
        float tv[16]; unpack8(q[0], tv); unpack8(q[1], tv+8);
        #pragma unroll
        for (int t=0;t<16;t++) u[t] = fmaf(sv, tv[t], u[t]);
    }
    #pragma unroll
    for (int t=0;t<16;t++) {
        #pragma unroll
        for (int o=32; o; o>>=1) u[t] += __shfl_xor(u[t], o, 64);
    }
    if (!lane) {
        #pragma unroll
        for (int t=0;t<16;t++) ur[wv][t] = u[t];
    }
    __syncthreads();
    if (tid < 16) uv[tid] = ur[0][tid]+ur[1][tid]+ur[2][tid]+ur[3][tid];
}

// ---------------------------------------------------------------------------
// K4: gemm2 + last-block epilogue. 256 blocks x 256 threads (full-grid
// parallelism preserved — the R8 lesson). Work mapping identical to the
// verified R6 k_gemm2: w=b*4+wv -> kc=w&15, tile=(w>>4): jt=tile>>1,
// dt=tile&1. Block reduces its 4 waves' partials in LDS, writes one
// 16x16 partial, takes a device-scope ticket; the 4th block of each tile
// sums the 4 partials + self terms (u1·B2T + v2·A2T) + leaky-ReLU -> out.
// ---------------------------------------------------------------------------
__global__ __launch_bounds__(256) void k_gemm2(
    const u16* __restrict__ W1c, const u16* __restrict__ W2c,
    const u16* __restrict__ A2T, const u16* __restrict__ B2T,
    const float* __restrict__ u1, const float* __restrict__ v2,
    float* __restrict__ tempP, int* __restrict__ cnt, float* __restrict__ out)
{
    const int tid = threadIdx.x;
    const int b = blockIdx.x;            // 0..255
    const int wv = tid >> 6, lane = tid & 63, l15 = lane & 15, quad = lane >> 4;
    const int tile = b >> 2;             // 0..63
    const int jt = tile >> 1, dt = tile & 1;
    const int kc = (b & 3)*4 + wv;       // 0..15
    __shared__ alignas(16) float sred[4][272];
    __shared__ int lastFlag;

    size_t aRow = (size_t)(jt*16 + l15)*8192;
    size_t bRow = (size_t)(dt*16 + l15)*8192;
    int kt0 = kc*512 + quad*8;
    f4 acc = {0.f, 0.f, 0.f, 0.f};
    #pragma unroll
    for (int s = 0; s < 16; s++) {
        int kt = kt0 + s*32;
        bf8 aw1 = *(const bf8*)(W1c + aRow + kt);
        bf8 ba2 = *(const bf8*)(A2T + bRow + kt);
        acc = __builtin_amdgcn_mfma_f32_16x16x32_bf16(aw1, ba2, acc, 0, 0, 0);
        bf8 aw2 = *(const bf8*)(W2c + aRow + kt);
        bf8 bb2 = *(const bf8*)(B2T + bRow + kt);
        acc = __builtin_amdgcn_mfma_f32_16x16x32_bf16(aw2, bb2, acc, 0, 0, 0);
    }
    #pragma unroll
    for (int r = 0; r < 4; r++)
        sred[wv][(quad*4+r)*17 + l15] = acc[r];
    __syncthreads();
    const int row = tid >> 4, col = tid & 15;
    float p = sred[0][row*17+col] + sred[1][row*17+col]
            + sred[2][row*17+col] + sred[3][row*17+col];
    tempP[(size_t)b*256 + row*16 + col] = p;
    __threadfence();                       // release partial device-wide
    __syncthreads();                       // all threads' fences done
    if (tid == 0) lastFlag = (atomicAdd(&cnt[tile], 1) == 3);
    __syncthreads();
    if (lastFlag) {
        __threadfence();                   // acquire: invalidate stale caches
        float a = 0.f;
        #pragma unroll
        for (int g = 0; g < 4; g++)
            a += tempP[(size_t)(tile*4 + g)*256 + row*16 + col];
        int j = jt*16 + row, d = dt*16 + col;
        const uint4* pb2 = (const uint4*)(B2T + (size_t)d*8192 + j*16);
        const uint4* pa2 = (const uint4*)(A2T + (size_t)d*8192 + j*16);
        float bv[16], av[16];
        unpack8(pb2[0], bv); unpack8(pb2[1], bv+8);
        unpack8(pa2[0], av); unpack8(pa2[1], av+8);
        float self = 0.f;
        #pragma unroll
        for (int t = 0; t < 16; t++)
            self += u1[(size_t)j*TP + t]*bv[t] + v2[(size_t)j*TP + t]*av[t];
        float val = a + self;
        out[(size_t)j*DD + d] = fmaxf(val, 0.2f*val);
    }
}

// ---------------------------------------------------------------------------
extern "C" void kernel_launch(void* const* d_in, const int* in_sizes, int n_in,
                              void* d_out, int out_size, void* d_ws, size_t ws_size,
                              hipStream_t stream)
{
    (void)in_sizes; (void)n_in; (void)out_size; (void)ws_size;
    const float* x   = (const float*)d_in[0];
    const float* adj = (const float*)d_in[1];
    const float* W1  = (const float*)d_in[2];
    const float* W2  = (const float*)d_in[3];
    const float* W3  = (const float*)d_in[4];

    char* ws = (char*)d_ws;
    u16*   adjP = (u16*)(ws);                   // 8 MB
    u16*   adjPT= (u16*)(ws + 0x800000);        // 8 MB
    u16*   W1c  = (u16*)(ws + 0x1000000);       // 8 MB
    u16*   W2c  = (u16*)(ws + 0x1800000);       // 8 MB
    u16*   A1   = (u16*)(ws + 0x2000000);       // 512 KB each
    u16*   B1   = (u16*)(ws + 0x2080000);
    u16*   A2T  = (u16*)(ws + 0x2100000);
    u16*   B2T  = (u16*)(ws + 0x2180000);
    u16*   Qb   = (u16*)(ws + 0x2200000);       // 32 KB
    float* QAd  = (float*)(ws + 0x2210000);
    float* QB   = (float*)(ws + 0x2220000);
    float* u1   = (float*)(ws + 0x2230000);
    float* v2   = (float*)(ws + 0x2240000);
    int*   cnt  = (int*)  (ws + 0x2250000);     // 64 tile tickets
    float* tempP= (float*)(ws + 0x2260000);     // 256 KB
    float* L1   = (float*)(ws + 0x2300000);     // 1 MB
    float* L2T  = (float*)(ws + 0x2400000);     // 1 MB

    k_prep_adjp<<<768, 256, 0, stream>>>(x, W1, W2, W3, adj,
                                         A1, B1, A2T, B2T, Qb, QAd, QB, adjP, adjPT, cnt);
    k_logits<<<dim3(32,32), 256, 0, stream>>>(Qb, A1, B1, adjP, adjPT, QAd, QB, L1, L2T);
    k_softmax_w<<<1024, 256, 0, stream>>>(L1, L2T, adjP, adjPT, W1c, W2c, u1, v2);
    k_gemm2<<<256, 256, 0, stream>>>(W1c, W2c, A2T, B2T, u1, v2, tempP, cnt, (float*)d_out);
}

// Round 10
// 115.219 us; speedup vs baseline: 1.2069x; 1.2069x over previous
//
#include <hip/hip_runtime.h>
#include <hip/hip_bf16.h>

#define NNODE 512
#define CCH   16
#define TT    15
#define TP    16
#define HH    32
#define DD    32

typedef unsigned short u16;
typedef unsigned int   u32;
typedef short bf8 __attribute__((ext_vector_type(8)));   // 8 bf16 = 4 VGPR (MFMA A/B frag)
typedef float f4  __attribute__((ext_vector_type(4)));   // MFMA C/D frag

__device__ __forceinline__ float bf2f(u16 v) {
    union { u32 u; float f; } x; x.u = ((u32)v) << 16; return x.f;
}
__device__ __forceinline__ u16 f2bf(float f) {
    union { float f; u32 u; } x; x.f = f;
    u32 u = x.u;
    return (u16)((u + 0x7FFFu + ((u >> 16) & 1u)) >> 16);
}
__device__ __forceinline__ void unpack8(uint4 p, float* o) {
    o[0]=bf2f((u16)(p.x & 0xffffu)); o[1]=bf2f((u16)(p.x >> 16));
    o[2]=bf2f((u16)(p.y & 0xffffu)); o[3]=bf2f((u16)(p.y >> 16));
    o[4]=bf2f((u16)(p.z & 0xffffu)); o[5]=bf2f((u16)(p.z >> 16));
    o[6]=bf2f((u16)(p.w & 0xffffu)); o[7]=bf2f((u16)(p.w >> 16));
}
__device__ __forceinline__ uint4 pack8(const u16* v) {
    return make_uint4((u32)v[0]|((u32)v[1]<<16), (u32)v[2]|((u32)v[3]<<16),
                      (u32)v[4]|((u32)v[5]<<16), (u32)v[6]|((u32)v[7]<<16));
}

// ---------------------------------------------------------------------------
// K1: blocks 0..511: per-node prep: A1/B1 bf16 [n][t*32+h], Qb bf16,
//     QAd/QB f32, A2T/B2T [d][(k=n)*16+t] via coalesced u32 stores.
//     blocks 512..767: 32x32 adjacency tiles -> adjP[n][m*16+t] AND
//     adjPT[m][n*16+t] (bf16, diag folded into t=15).
// ---------------------------------------------------------------------------
__global__ __launch_bounds__(256) void k_prep_adjp(
    const float* __restrict__ x, const float* __restrict__ W1,
    const float* __restrict__ W2, const float* __restrict__ W3,
    const float* __restrict__ adj,
    u16* __restrict__ A1, u16* __restrict__ B1,
    u16* __restrict__ A2T, u16* __restrict__ B2T,
    u16* __restrict__ Qb, float* __restrict__ QAd, float* __restrict__ QB,
    u16* __restrict__ adjP, u16* __restrict__ adjPT)
{
    int tid = threadIdx.x;
    if (blockIdx.x < 512) {
        int n = blockIdx.x;
        __shared__ alignas(16) float xs[CCH];
        __shared__ alignas(16) float A1row[512], B1row[512];
        __shared__ alignas(16) float A2row[512], B2row[512];
        __shared__ alignas(16) float Qs[HH];
        if (tid < CCH) xs[tid] = x[n*CCH + tid];
        __syncthreads();
        float xr[CCH];
        #pragma unroll
        for (int i=0;i<CCH;i++) xr[i]=xs[i];
        #pragma unroll
        for (int rep=0; rep<2; rep++) {
            int c = tid + rep*256;
            float a1=0.f,b1=0.f,a2=0.f,b2=0.f;
            #pragma unroll
            for (int i=0;i<CCH;i++) {
                a1 += xr[i]*W1[i*512 + c];
                b1 += xr[i]*W1[(CCH+i)*512 + c];
                a2 += xr[i]*W2[i*512 + c];
                b2 += xr[i]*W2[(CCH+i)*512 + c];
            }
            A1[(size_t)n*512 + c]=f2bf(a1); B1[(size_t)n*512 + c]=f2bf(b1);
            A1row[c]=a1; B1row[c]=b1; A2row[c]=a2; B2row[c]=b2;
        }
        if (tid < HH) {
            float q=0.f;
            #pragma unroll
            for (int i=0;i<CCH;i++) q += xr[i]*W3[i*HH + tid];
            Qs[tid]=q; Qb[(size_t)n*HH + tid]=f2bf(q);
        }
        __syncthreads();
        if (tid < TP) {
            float qa=0.f, qb=0.f;
            #pragma unroll
            for (int h=0;h<HH;h++) { qa += Qs[h]*A1row[tid*HH+h]; qb += Qs[h]*B1row[tid*HH+h]; }
            QAd[(size_t)n*TP + tid]=qa; QB[(size_t)n*TP + tid]=qb;
        }
        {   // A2T/B2T: [d][n*16+t]; coalesced u32 stores
            int d = tid >> 3, t0 = (tid & 7) * 2;
            u32 pa = (u32)f2bf(A2row[t0*32 + d]) | ((u32)f2bf(A2row[(t0+1)*32 + d]) << 16);
            u32 pb = (u32)f2bf(B2row[t0*32 + d]) | ((u32)f2bf(B2row[(t0+1)*32 + d]) << 16);
            *(u32*)(A2T + (size_t)d*8192 + n*16 + t0) = pa;
            *(u32*)(B2T + (size_t)d*8192 + n*16 + t0) = pb;
        }
    } else {
        int b = blockIdx.x - 512;            // 0..255
        int n0 = (b >> 4) * 32, m0 = (b & 15) * 32;
        __shared__ alignas(16) u16 s[32*520];  // stride 520 (1040B=65*16)
        #pragma unroll
        for (int i = 0; i < 60; i++) {
            int e = tid + i*256;
            int nl = e / 480; int rem = e - nl*480;
            int ml = rem / 15; int t = rem - ml*15;
            float v = adj[((size_t)(n0+nl)*512 + (m0+ml))*TT + t];
            s[nl*520 + ml*16 + t] = f2bf(v);
        }
        #pragma unroll
        for (int i = 0; i < 4; i++) {
            int e = tid + i*256; int nl = e >> 5, ml = e & 31;
            s[nl*520 + ml*16 + 15] = ((n0+nl) == (m0+ml)) ? (u16)0x3F80 : (u16)0;
        }
        __syncthreads();
        #pragma unroll
        for (int i = 0; i < 8; i++) {        // adjP: 32 rows x 1KB
            int c = tid + i*256;
            int nl = c >> 6, off = (c & 63) * 8;
            uint4 vv = *(const uint4*)(s + nl*520 + off);
            *(uint4*)(adjP + (size_t)(n0+nl)*8192 + m0*16 + off) = vv;
        }
        #pragma unroll
        for (int i = 0; i < 8; i++) {        // adjPT: 32 rows x 1KB (transposed)
            int c = tid + i*256;
            int ml = c >> 6, nlh = c & 63, nl = nlh >> 1, half = nlh & 1;
            uint4 vv = *(const uint4*)(s + nl*520 + ml*16 + half*8);
            *(uint4*)(adjPT + (size_t)(m0+ml)*8192 + (n0+nl)*16 + half*8) = vv;
        }
    }
}

// ---------------------------------------------------------------------------
// K2: fused logits: MFMA the directed dot-tensors, combine in-register,
// t-sum via 16-lane xor shuffles. L2 written transposed.
// ---------------------------------------------------------------------------
__global__ __launch_bounds__(256) void k_logits(
    const u16* __restrict__ Qb, const u16* __restrict__ A1, const u16* __restrict__ B1,
    const u16* __restrict__ adjP, const u16* __restrict__ adjPT,
    const float* __restrict__ QAd, const float* __restrict__ QB,
    float* __restrict__ L1, float* __restrict__ L2T)
{
    const int m0 = blockIdx.x * 16, n0 = blockIdx.y * 16;
    const int tid = threadIdx.x;
    const int wv = tid >> 6, lane = tid & 63, l15 = lane & 15, quad = lane >> 4;
    __shared__ alignas(16) float sL1[16*17];
    __shared__ alignas(16) float sL2[16*17];

    bf8 afragN = *(const bf8*)(Qb + (size_t)(n0 + l15)*32 + quad*8);
    bf8 afragM = *(const bf8*)(Qb + (size_t)(m0 + l15)*32 + quad*8);

    f4 accG[4], accH[4];
    #pragma unroll
    for (int j = 0; j < 4; j++) {
        int m = m0 + wv*4 + j;
        int n = n0 + wv*4 + j;
        bf8 bG = *(const bf8*)(A1 + (size_t)m*512 + l15*32 + quad*8);
        bf8 bH = *(const bf8*)(B1 + (size_t)n*512 + l15*32 + quad*8);
        f4 z = {0.f,0.f,0.f,0.f};
        accG[j] = __builtin_amdgcn_mfma_f32_16x16x32_bf16(afragN, bG, z, 0, 0, 0);
        accH[j] = __builtin_amdgcn_mfma_f32_16x16x32_bf16(afragM, bH, z, 0, 0, 0);
    }

    #pragma unroll
    for (int j = 0; j < 4; j++) {
        int m = m0 + wv*4 + j;
        #pragma unroll
        for (int r = 0; r < 4; r++) {
            int n = n0 + quad*4 + r;
            float a  = bf2f(adjP [(size_t)n*8192 + m*16 + l15]);
            float at = bf2f(adjPT[(size_t)n*8192 + m*16 + l15]);
            float v = a*accG[j][r] + at*QB[n*16 + l15];
            #pragma unroll
            for (int o = 1; o < 16; o <<= 1) v += __shfl_xor(v, o, 64);
            if (l15 == 0) sL1[(quad*4+r)*17 + wv*4 + j] = v;
        }
    }
    #pragma unroll
    for (int j = 0; j < 4; j++) {
        int n = n0 + wv*4 + j;
        #pragma unroll
        for (int r = 0; r < 4; r++) {
            int m = m0 + quad*4 + r;
            float a  = bf2f(adjP [(size_t)n*8192 + m*16 + l15]);
            float at = bf2f(adjPT[(size_t)n*8192 + m*16 + l15]);
            float v = a*QAd[m*16 + l15] + at*accH[j][r];
            #pragma unroll
            for (int o = 1; o < 16; o <<= 1) v += __shfl_xor(v, o, 64);
            if (l15 == 0) sL2[(quad*4+r)*17 + wv*4 + j] = v;
        }
    }
    __syncthreads();
    int row = tid >> 4, col = tid & 15;
    L1 [(size_t)(n0+row)*NNODE + m0 + col] = sL1[row*17+col];
    L2T[(size_t)(m0+row)*NNODE + n0 + col] = sL2[row*17+col];
}

// ---------------------------------------------------------------------------
// K3: softmax over a 512-row + FUSED W-build and u/v reduction.
// ---------------------------------------------------------------------------
__global__ __launch_bounds__(256) void k_softmax_w(
    const float* __restrict__ L1, const float* __restrict__ L2T,
    const u16* __restrict__ adjP, const u16* __restrict__ adjPT,
    u16* __restrict__ W1c, u16* __restrict__ W2c,
    float* __restrict__ u1, float* __restrict__ v2)
{
    int b = blockIdx.x, tid = threadIdx.x;
    bool first = b < NNODE;
    int j = first ? b : b - NNODE;
    const float* row = first ? (L1 + (size_t)j*NNODE) : (L2T + (size_t)j*NNODE);
    u16* W  = (first ? W1c : W2c) + (size_t)j*8192;
    float* uv = (first ? u1 : v2) + (size_t)j*TP;

    float v0 = row[tid], v1 = row[tid+256];
    float mx = fmaxf(v0, v1);
    #pragma unroll
    for (int o=32; o; o>>=1) mx = fmaxf(mx, __shfl_xor(mx, o, 64));
    __shared__ alignas(16) float red[4], red2[4], ur[4][16];
    int lane = tid & 63, wv = tid >> 6;
    if (!lane) red[wv] = mx;
    __syncthreads();
    mx = fmaxf(fmaxf(red[0],red[1]), fmaxf(red[2],red[3]));
    float e0 = __expf(v0 - mx), e1 = __expf(v1 - mx);
    float sm = e0 + e1;
    #pragma unroll
    for (int o=32; o; o>>=1) sm += __shfl_xor(sm, o, 64);
    if (!lane) red2[wv] = sm;
    __syncthreads();
    float inv = 1.0f / (red2[0]+red2[1]+red2[2]+red2[3]);
    float sa = e0*inv, sb = e1*inv;

    const u16* ap = adjP  + (size_t)j*8192;
    const u16* tp = adjPT + (size_t)j*8192;
    float u[16];
    #pragma unroll
    for (int t=0;t<16;t++) u[t]=0.f;
    #pragma unroll
    for (int half = 0; half < 2; half++) {
        int k = tid + half*256;
        float sv = half ? sb : sa;
        const uint4* p = (const uint4*)(ap + k*16);
        float av[16]; unpack8(p[0], av); unpack8(p[1], av+8);
        u16 o16[16];
        #pragma unroll
        for (int t=0;t<16;t++) o16[t] = f2bf(sv*av[t]);
        uint4* wp = (uint4*)(W + k*16);
        wp[0] = pack8(o16); wp[1] = pack8(o16+8);
        const uint4* q = (const uint4*)(tp + k*16);
        float tv[16]; unpack8(q[0], tv); unpack8(q[1], tv+8);
        #pragma unroll
        for (int t=0;t<16;t++) u[t] = fmaf(sv, tv[t], u[t]);
    }
    #pragma unroll
    for (int t=0;t<16;t++) {
        #pragma unroll
        for (int o=32; o; o>>=1) u[t] += __shfl_xor(u[t], o, 64);
    }
    if (!lane) {
        #pragma unroll
        for (int t=0;t<16;t++) ur[wv][t] = u[t];
    }
    __syncthreads();
    if (tid < 16) uv[tid] = ur[0][tid]+ur[1][tid]+ur[2][tid]+ur[3][tid];
}

// ---------------------------------------------------------------------------
// K4: MFMA GEMM temp[j,d] = W1c[j,:]·A2T[d,:] + W2c[j,:]·B2T[d,:]
// (M=512, N=32, K=8192 split into 16 k-chunks; partials to tempP)
// ---------------------------------------------------------------------------
__global__ __launch_bounds__(256) void k_gemm2(
    const u16* __restrict__ W1c, const u16* __restrict__ W2c,
    const u16* __restrict__ A2T, const u16* __restrict__ B2T,
    float* __restrict__ tempP)
{
    int tid = threadIdx.x;
    int wv = tid >> 6, lane = tid & 63, l15 = lane & 15, quad = lane >> 4;
    int w = blockIdx.x*4 + wv;             // 0..1023
    int kc = w & 15, dt = (w >> 4) & 1, jt = w >> 5;
    size_t aRow = (size_t)(jt*16 + l15)*8192;
    size_t bRow = (size_t)(dt*16 + l15)*8192;
    int kt0 = kc*512 + quad*8;
    f4 acc = {0.f, 0.f, 0.f, 0.f};
    #pragma unroll
    for (int s = 0; s < 16; s++) {
        int kt = kt0 + s*32;
        bf8 aw1 = *(const bf8*)(W1c + aRow + kt);
        bf8 ba2 = *(const bf8*)(A2T + bRow + kt);
        acc = __builtin_amdgcn_mfma_f32_16x16x32_bf16(aw1, ba2, acc, 0, 0, 0);
        bf8 aw2 = *(const bf8*)(W2c + aRow + kt);
        bf8 bb2 = *(const bf8*)(B2T + bRow + kt);
        acc = __builtin_amdgcn_mfma_f32_16x16x32_bf16(aw2, bb2, acc, 0, 0, 0);
    }
    #pragma unroll
    for (int r = 0; r < 4; r++)
        tempP[((size_t)kc*NNODE + jt*16 + quad*4 + r)*DD + dt*16 + l15] = acc[r];
}

// ---------------------------------------------------------------------------
// K5: reduce k-chunk partials, add self terms (u1·B2T + v2·A2T), lrelu, out.
// ---------------------------------------------------------------------------
__global__ __launch_bounds__(256) void k_final(
    const float* __restrict__ tempP, const float* __restrict__ u1, const float* __restrict__ v2,
    const u16* __restrict__ A2T, const u16* __restrict__ B2T, float* __restrict__ out)
{
    int base = blockIdx.x * 256 + threadIdx.x;   // 0..16383 over 64 blocks
    int j = base >> 5, d = base & 31;
    float acc = 0.f;
    #pragma unroll
    for (int kc=0;kc<16;kc++) acc += tempP[((size_t)kc*NNODE + j)*DD + d];
    const uint4* pb2 = (const uint4*)(B2T + (size_t)d*8192 + j*16);
    const uint4* pa2 = (const uint4*)(A2T + (size_t)d*8192 + j*16);
    float bv[16], av[16];
    unpack8(pb2[0], bv); unpack8(pb2[1], bv+8);
    unpack8(pa2[0], av); unpack8(pa2[1], av+8);
    #pragma unroll
    for (int t = 0; t < 16; t++)
        acc += u1[(size_t)j*TP + t]*bv[t] + v2[(size_t)j*TP + t]*av[t];
    out[(size_t)j*DD + d] = fmaxf(acc, 0.2f*acc);
}

// ---------------------------------------------------------------------------
extern "C" void kernel_launch(void* const* d_in, const int* in_sizes, int n_in,
                              void* d_out, int out_size, void* d_ws, size_t ws_size,
                              hipStream_t stream)
{
    (void)in_sizes; (void)n_in; (void)out_size; (void)ws_size;
    const float* x   = (const float*)d_in[0];
    const float* adj = (const float*)d_in[1];
    const float* W1  = (const float*)d_in[2];
    const float* W2  = (const float*)d_in[3];
    const float* W3  = (const float*)d_in[4];

    char* ws = (char*)d_ws;
    u16*   adjP = (u16*)(ws);                   // 8 MB
    u16*   adjPT= (u16*)(ws + 0x800000);        // 8 MB
    u16*   W1c  = (u16*)(ws + 0x1000000);       // 8 MB
    u16*   W2c  = (u16*)(ws + 0x1800000);       // 8 MB
    u16*   A1   = (u16*)(ws + 0x2000000);       // 512 KB each
    u16*   B1   = (u16*)(ws + 0x2080000);
    u16*   A2T  = (u16*)(ws + 0x2100000);
    u16*   B2T  = (u16*)(ws + 0x2180000);
    u16*   Qb   = (u16*)(ws + 0x2200000);       // 32 KB
    float* QAd  = (float*)(ws + 0x2210000);
    float* QB   = (float*)(ws + 0x2220000);
    float* u1   = (float*)(ws + 0x2230000);
    float* v2   = (float*)(ws + 0x2240000);
    float* L1   = (float*)(ws + 0x2300000);     // 1 MB
    float* L2T  = (float*)(ws + 0x2400000);     // 1 MB
    float* tempP= (float*)(ws + 0x2500000);     // 1 MB

    k_prep_adjp<<<768, 256, 0, stream>>>(x, W1, W2, W3, adj,
                                         A1, B1, A2T, B2T, Qb, QAd, QB, adjP, adjPT);
    k_logits<<<dim3(32,32), 256, 0, stream>>>(Qb, A1, B1, adjP, adjPT, QAd, QB, L1, L2T);
    k_softmax_w<<<1024, 256, 0, stream>>>(L1, L2T, adjP, adjPT, W1c, W2c, u1, v2);
    k_gemm2<<<256, 256, 0, stream>>>(W1c, W2c, A2T, B2T, tempP);
    k_final<<<64, 256, 0, stream>>>(tempP, u1, v2, A2T, B2T, (float*)d_out);
}